// Round 1
// baseline (445.610 us; speedup 1.0000x reference)
//
#include <hip/hip_runtime.h>
#include <hip/hip_bf16.h>
#include <stdint.h>

// WaveletLinearLayer: out = HaarDWT2(x) @ W.T + b
// == x-side fused split-K GEMM: out[m,n] = b[n] + 0.5 * sum_k u[m,k]*W[n,k]
// where u = unscaled Haar combos of 2x2 spatial quads of x.
// M=256 (batch), N=64 (out), K=262144. Memory-bound: 335 MB compulsory.

#define IN_K 262144
#define HS   128
#define LDA  72   // LDS row pitch in shorts: 64 + 8 pad -> 144 B = 9*16 B

typedef short bf16x8 __attribute__((ext_vector_type(8)));
typedef float f32x4  __attribute__((ext_vector_type(4)));

__device__ __forceinline__ uint32_t pack2_bf16(float a, float b) {
    // round-to-nearest-even fp32 -> bf16, packed low(a)|high(b)
    uint32_t ua = __float_as_uint(a);
    uint32_t ub = __float_as_uint(b);
    ua = (ua + 0x7fffu + ((ua >> 16) & 1u)) >> 16;
    ub = (ub + 0x7fffu + ((ub >> 16) & 1u)) >> 16;
    return ua | (ub << 16);
}

// Grid-stride over 4096 K-steps. Step s -> (c,i,jg): channel c in [0,4),
// spatial row-pair i in [0,128), j-group jg in [0,8) (16 j's each).
// Per step: stage A-tile (256 x 64 bf16, k = q*16+jl) from x quads (Haar on
// the fly), B-tile (64 x 64 bf16) from W directly, then 16x16x32 bf16 MFMA.
__global__ __launch_bounds__(512) void wavelet_gemm(
    const float* __restrict__ x, const float* __restrict__ W,
    float* __restrict__ part)
{
    __shared__ short Ash[256 * LDA];   // 36864 B
    __shared__ short Bsh[64 * LDA];    //  9216 B

    const int tid  = threadIdx.x;
    const int lane = tid & 63;
    const int wave = tid >> 6;       // 8 waves
    const int l16  = lane & 15;
    const int l4   = lane >> 4;      // quad 0..3
    const int wm   = wave * 32;      // each wave: 32 rows x 64 cols

    f32x4 acc[2][4];
#pragma unroll
    for (int mi = 0; mi < 2; mi++)
#pragma unroll
        for (int ni = 0; ni < 4; ni++)
            acc[mi][ni] = (f32x4){0.f, 0.f, 0.f, 0.f};

    for (int s = blockIdx.x; s < 4096; s += gridDim.x) {
        const int ci = s >> 3;
        const int jg = s & 7;
        const int c  = ci >> 7;
        const int i  = ci & 127;

        // ---- stage x -> Ash (Haar, unscaled: u = 2*t) ----
        // x rows 2i and 2i+1 of channel c are contiguous (512 floats).
        const int row0 = (c * 256 + 2 * i) * 256 + 32 * jg;
#pragma unroll
        for (int p = tid; p < 2048; p += 512) {   // 256 b x 8 jj4
            const int b   = p >> 3;
            const int jj4 = p & 7;                // float4 index within 32 cols
            const float4 f0 = *(const float4*)(x + (size_t)b * IN_K + row0 + jj4 * 4);
            const float4 f1 = *(const float4*)(x + (size_t)b * IN_K + row0 + 256 + jj4 * 4);
            // two j-elements per thread: jl and jl+1
            const float s1a = f0.x + f0.y, s2a = f1.x + f1.y;
            const float d1a = f0.x - f0.y, d2a = f1.x - f1.y;
            const float s1b = f0.z + f0.w, s2b = f1.z + f1.w;
            const float d1b = f0.z - f0.w, d2b = f1.z - f1.w;
            const int jl = jj4 * 2;
            short* arow = &Ash[b * LDA + jl];
            *(uint32_t*)(arow +  0) = pack2_bf16(s1a + s2a, s1b + s2b); // LL
            *(uint32_t*)(arow + 16) = pack2_bf16(s1a - s2a, s1b - s2b); // LH
            *(uint32_t*)(arow + 32) = pack2_bf16(d1a + d2a, d1b + d2b); // HL
            *(uint32_t*)(arow + 48) = pack2_bf16(d1a - d2a, d1b - d2b); // HH
        }

        // ---- stage W -> Bsh ----
        // t-col(q,jl) = (c*4+q)*16384 + i*128 + 16*jg + jl
#pragma unroll
        for (int v = tid; v < 1024; v += 512) {   // 64 o x 4 q x 4 jj4
            const int o   = v >> 4;
            const int q   = (v >> 2) & 3;
            const int jj4 = v & 3;
            const float4 f = *(const float4*)(W + (size_t)o * IN_K
                                + (c * 4 + q) * 16384 + i * 128 + 16 * jg + jj4 * 4);
            short* brow = &Bsh[o * LDA + q * 16 + jj4 * 4];
            *(uint32_t*)(brow + 0) = pack2_bf16(f.x, f.y);
            *(uint32_t*)(brow + 2) = pack2_bf16(f.z, f.w);
        }

        __syncthreads();

        // ---- MFMA over KB=64 (two K=32 halves) ----
#pragma unroll
        for (int kh = 0; kh < 2; kh++) {
            const int ko = kh * 32 + l4 * 8;
            bf16x8 a0 = *(const bf16x8*)&Ash[(wm + l16) * LDA + ko];
            bf16x8 a1 = *(const bf16x8*)&Ash[(wm + 16 + l16) * LDA + ko];
#pragma unroll
            for (int ni = 0; ni < 4; ni++) {
                bf16x8 bf = *(const bf16x8*)&Bsh[(ni * 16 + l16) * LDA + ko];
                acc[0][ni] = __builtin_amdgcn_mfma_f32_16x16x32_bf16(a0, bf, acc[0][ni], 0, 0, 0);
                acc[1][ni] = __builtin_amdgcn_mfma_f32_16x16x32_bf16(a1, bf, acc[1][ni], 0, 0, 0);
            }
        }

        __syncthreads();   // before next step overwrites LDS
    }

    // ---- epilogue: write 256x64 partial for this block ----
    // C/D layout: col = lane&15, row = (lane>>4)*4 + r
    float* p = part + (size_t)blockIdx.x * (256 * 64);
#pragma unroll
    for (int mi = 0; mi < 2; mi++)
#pragma unroll
        for (int ni = 0; ni < 4; ni++)
#pragma unroll
            for (int r = 0; r < 4; r++) {
                const int m = wm + mi * 16 + l4 * 4 + r;
                const int n = ni * 16 + l16;
                p[m * 64 + n] = acc[mi][ni][r];
            }
}

// out[e] = bias[e&63] + 0.5 * sum_blk part[blk][e]
// 256 blocks x 64 elems; 4 partial-groups per block reduced via LDS.
__global__ __launch_bounds__(256) void wavelet_reduce(
    const float* __restrict__ part, const float* __restrict__ bias,
    float* __restrict__ out, int nblk)
{
    __shared__ float red[4][64];
    const int e_l = threadIdx.x & 63;
    const int g   = threadIdx.x >> 6;
    const int e0  = blockIdx.x * 64;
    float acc = 0.f;
    for (int blk = g; blk < nblk; blk += 4)
        acc += part[(size_t)blk * 16384 + e0 + e_l];
    red[g][e_l] = acc;
    __syncthreads();
    if (g == 0) {
        const float v = red[0][e_l] + red[1][e_l] + red[2][e_l] + red[3][e_l];
        out[e0 + e_l] = 0.5f * v + bias[e_l];
    }
}

extern "C" void kernel_launch(void* const* d_in, const int* in_sizes, int n_in,
                              void* d_out, int out_size, void* d_ws, size_t ws_size,
                              hipStream_t stream)
{
    const float* x = (const float*)d_in[0];   // (256, 262144) fp32
    const float* W = (const float*)d_in[1];   // (64, 262144) fp32
    const float* b = (const float*)d_in[2];   // (64,) fp32
    float* out  = (float*)d_out;              // (256, 64) fp32
    float* part = (float*)d_ws;

    int nb = (int)(ws_size / (size_t)(16384 * 4));
    if (nb > 512) nb = 512;
    if (nb < 1)  nb = 1;

    wavelet_gemm<<<nb, 512, 0, stream>>>(x, W, part);
    wavelet_reduce<<<256, 256, 0, stream>>>(part, b, out, nb);
}